// Round 1
// 424.912 us; speedup vs baseline: 1.0337x; 1.0337x over previous
//
#include <hip/hip_runtime.h>

#define NN 32
#define CC 256
#define LL 1024
#define IC 128
#define R2 9
#define DA 9216
#define DOUT 131072
#define EPSF 1e-5f

typedef __attribute__((ext_vector_type(8))) short short8;
typedef __attribute__((ext_vector_type(4))) float f32x4;

__device__ __forceinline__ ushort bf_rne(float f) {
  union { float f; unsigned u; } v;
  v.f = f;
  unsigned u = v.u;
  u += 0x7FFF + ((u >> 16) & 1);
  return (ushort)(u >> 16);
}

// ---------------- K0: xt[n][l][c] bf16 <- x[n][c][l] fp32 -------------------
__global__ __launch_bounds__(256) void k_xt(const float* __restrict__ x,
                                            ushort* __restrict__ xt) {
  int n = blockIdx.y;
  int l = blockIdx.x * 128 + (threadIdx.x & 127);
  int chalf = (threadIdx.x >> 7) * 128;
  const float* xn = x + ((size_t)n * CC) * LL;
  ushort* xr = xt + ((size_t)n * LL + l) * CC + chalf;
#pragma unroll 4
  for (int c4 = 0; c4 < 32; c4++) {
    float a = xn[(size_t)(chalf + c4 * 4 + 0) * LL + l];
    float b = xn[(size_t)(chalf + c4 * 4 + 1) * LL + l];
    float c = xn[(size_t)(chalf + c4 * 4 + 2) * LL + l];
    float d = xn[(size_t)(chalf + c4 * 4 + 3) * LL + l];
    ushort4 o;
    o.x = bf_rne(a); o.y = bf_rne(b); o.z = bf_rne(c); o.w = bf_rne(d);
    *(ushort4*)(xr + c4 * 4) = o;
  }
}

// ---------------- K1: q = wq*x, k = wk*x via bf16 MFMA ----------------------
__global__ __launch_bounds__(256, 1) void k_qk(const ushort* __restrict__ xt,
                                               const float* __restrict__ wq,
                                               const float* __restrict__ wk,
                                               float* __restrict__ q,
                                               float* __restrict__ k) {
  int bx = blockIdx.x;
  int n = blockIdx.y;
  int mt = bx & 1, lt = bx >> 1;
  int l0 = lt * 256;
  int t = threadIdx.x;
  int lane = t & 63, wv = t >> 6;
  int m16 = lane & 15, kg = lane >> 4;
  const float* wrow = mt ? wk : wq;

  short8 a[2][8];
#pragma unroll
  for (int ms = 0; ms < 2; ms++)
#pragma unroll
    for (int kc = 0; kc < 8; kc++) {
      const float* ap =
          wrow + (size_t)(wv * 32 + ms * 16 + m16) * CC + kc * 32 + kg * 8;
      short8 v;
#pragma unroll
      for (int j = 0; j < 8; j++) v[j] = (short)bf_rne(ap[j]);
      a[ms][kc] = v;
    }

  f32x4 acc0[16], acc1[16];
#pragma unroll
  for (int i = 0; i < 16; i++) {
    acc0[i] = (f32x4){0.f, 0.f, 0.f, 0.f};
    acc1[i] = (f32x4){0.f, 0.f, 0.f, 0.f};
  }

  const ushort* xrow = xt + ((size_t)n * LL + l0 + m16) * CC + kg * 8;
#pragma unroll
  for (int kc = 0; kc < 8; kc++) {
#pragma unroll
    for (int ls = 0; ls < 16; ls++) {
      short8 b = *(const short8*)(xrow + (size_t)ls * 16 * CC + kc * 32);
      acc0[ls] =
          __builtin_amdgcn_mfma_f32_16x16x32_bf16(a[0][kc], b, acc0[ls], 0, 0, 0);
      acc1[ls] =
          __builtin_amdgcn_mfma_f32_16x16x32_bf16(a[1][kc], b, acc1[ls], 0, 0, 0);
    }
  }

  float* outp = (mt ? k : q) + (size_t)n * IC * LL;
  int mq = kg * 4;
#pragma unroll
  for (int ls = 0; ls < 16; ls++) {
    int col = l0 + ls * 16 + m16;
#pragma unroll
    for (int r = 0; r < 4; r++) {
      outp[(size_t)(wv * 32 + mq + r) * LL + col] = acc0[ls][r];
      outp[(size_t)(wv * 32 + 16 + mq + r) * LL + col] = acc1[ls][r];
    }
  }
}

// ---------------- K2: local 3x3 attention scores, f2 += 2*(q.k_patch) -------
__global__ __launch_bounds__(256) void k_attn(const float* __restrict__ q,
                                              const float* __restrict__ k,
                                              float* __restrict__ f2) {
  int n = blockIdx.x;
  int c0 = blockIdx.y * 32;
  int l = blockIdx.z * 256 + threadIdx.x;
  int h = l >> 5, w = l & 31;
  const float* qn = q + (size_t)n * IC * LL;
  const float* kn = k + (size_t)n * IC * LL;
  bool val[9];
  int off[9];
#pragma unroll
  for (int i = 0; i < 3; i++)
#pragma unroll
    for (int j = 0; j < 3; j++) {
      int r = i * 3 + j;
      int hh = h + i - 1, ww = w + j - 1;
      val[r] = (hh >= 0 && hh < 32 && ww >= 0 && ww < 32);
      off[r] = hh * 32 + ww;
    }
  float acc[9];
#pragma unroll
  for (int r = 0; r < 9; r++) acc[r] = 0.f;
#pragma unroll 4
  for (int cc = 0; cc < 32; cc++) {
    int c = c0 + cc;
    float qv = qn[c * LL + l];
    const float* kc = kn + c * LL;
#pragma unroll
    for (int r = 0; r < 9; r++) {
      float kv = val[r] ? kc[off[r]] : 0.f;
      acc[r] += qv * kv;
    }
  }
#pragma unroll
  for (int r = 0; r < 9; r++)
    atomicAdd(&f2[(size_t)n * DA + r * LL + l], 2.f * acc[r]);
}

// ---------------- K3: LayerNorm over 9216, in place -------------------------
__global__ __launch_bounds__(256) void k_ln1(float* __restrict__ f2,
                                             const float* __restrict__ g1,
                                             const float* __restrict__ b1) {
  int n = blockIdx.x, t = threadIdx.x;
  float* row = f2 + (size_t)n * DA;
  float4 v[9];
  float s = 0.f, ss = 0.f;
#pragma unroll
  for (int kk = 0; kk < 9; kk++) {
    v[kk] = ((const float4*)row)[t + kk * 256];
    s += v[kk].x + v[kk].y + v[kk].z + v[kk].w;
    ss += v[kk].x * v[kk].x + v[kk].y * v[kk].y + v[kk].z * v[kk].z +
          v[kk].w * v[kk].w;
  }
#pragma unroll
  for (int o = 32; o; o >>= 1) {
    s += __shfl_down(s, o);
    ss += __shfl_down(ss, o);
  }
  __shared__ float ps[4], pss[4], stats[2];
  int wid = t >> 6, lid = t & 63;
  if (lid == 0) { ps[wid] = s; pss[wid] = ss; }
  __syncthreads();
  if (t == 0) {
    float S = ps[0] + ps[1] + ps[2] + ps[3];
    float SS = pss[0] + pss[1] + pss[2] + pss[3];
    float mu = S / DA;
    float var = SS / DA - mu * mu;
    stats[0] = mu;
    stats[1] = rsqrtf(var + EPSF);
  }
  __syncthreads();
  float mu = stats[0], rs = stats[1];
#pragma unroll
  for (int kk = 0; kk < 9; kk++) {
    float4 g = ((const float4*)g1)[t + kk * 256];
    float4 b = ((const float4*)b1)[t + kk * 256];
    float4 o;
    o.x = (v[kk].x - mu) * rs * g.x + b.x;
    o.y = (v[kk].y - mu) * rs * g.y + b.y;
    o.z = (v[kk].z - mu) * rs * g.z + b.z;
    o.w = (v[kk].w - mu) * rs * g.w + b.w;
    ((float4*)row)[t + kk * 256] = o;
  }
}

// ---------------- K4: h1 = relu(fln @ w1^T + b1), n-split x4 ----------------
__global__ __launch_bounds__(256) void k_ffn1(const float* __restrict__ fln,
                                              const float* __restrict__ w1,
                                              const float* __restrict__ b1,
                                              float* __restrict__ h1) {
  int o = blockIdx.x, nsb = blockIdx.y * 8, t = threadIdx.x;
  float acc[8];
#pragma unroll
  for (int i = 0; i < 8; i++) acc[i] = 0.f;
  const float4* w1r = (const float4*)(w1 + (size_t)o * DA);
  for (int kk = 0; kk < 9; kk++) {
    float4 wv = w1r[t + kk * 256];
#pragma unroll
    for (int i = 0; i < 8; i++) {
      float4 fv = ((const float4*)(fln + (size_t)(nsb + i) * DA))[t + kk * 256];
      acc[i] += wv.x * fv.x + wv.y * fv.y + wv.z * fv.z + wv.w * fv.w;
    }
  }
#pragma unroll
  for (int i = 0; i < 8; i++)
#pragma unroll
    for (int s = 32; s; s >>= 1) acc[i] += __shfl_down(acc[i], s);
  __shared__ float part[4][8];
  int wid = t >> 6, lid = t & 63;
  if (lid == 0) {
#pragma unroll
    for (int i = 0; i < 8; i++) part[wid][i] = acc[i];
  }
  __syncthreads();
  if (t < 8) {
    float sum = part[0][t] + part[1][t] + part[2][t] + part[3][t] + b1[o];
    h1[(size_t)(nsb + t) * CC + o] = fmaxf(sum, 0.f);
  }
}

// ---------------- K5: h2 = h1 @ w2^T + b2, per-block LN2 partials -----------
// Rewritten: grid 512 (j-tiles of 256), block 256 = 4 waves.
// Wave w owns n rows [8w, 8w+8); lane owns j quad [j0+4*lane, +4).
// Thread tile 8n x 4j -> 1 ds_read_b128 per 32 FMAs (LDS off critical path).
// h1 (32KB, L1/L2-resident) read direct from global, wave-uniform broadcast.
// wt stride 260: bank = (16q+4r+row)%32 -> only free 2-way write conflict.
// Stage c-step 32, next stage prefetched into regs during compute (T14).
__global__ __launch_bounds__(256) void k_ffn2(const float* __restrict__ h1,
                                              const float* __restrict__ w2,
                                              const float* __restrict__ b2,
                                              float* __restrict__ h2,
                                              float* __restrict__ st_part) {
  __shared__ float wt[32 * 260];   // 33.3 KB
  int t = threadIdx.x;
  int j0 = blockIdx.x * 256;
  int lane = t & 63, wv = t >> 6;
  int n4 = wv * 8;
  int jj = lane * 4;
  const float* h1w = h1 + (size_t)n4 * CC;

  float4 acc[8];
#pragma unroll
  for (int i = 0; i < 8; i++) acc[i] = make_float4(0.f, 0.f, 0.f, 0.f);

  // prologue: load stage 0 into regs
  float4 stg[8];
#pragma unroll
  for (int u = 0; u < 8; u++) {
    int f = t + u * 256;
    int row = (f >> 2) & 255, qq = f & 3, hh = f >> 10;
    stg[u] = *(const float4*)(w2 + (size_t)(j0 + row) * CC + hh * 16 + qq * 4);
  }

  for (int c0 = 0; c0 < CC; c0 += 32) {
    __syncthreads();   // prev compute done reading wt
#pragma unroll
    for (int u = 0; u < 8; u++) {
      int f = t + u * 256;
      int row = (f >> 2) & 255, qq = f & 3, hh = f >> 10;
      int cc = hh * 16 + qq * 4;
      wt[(cc + 0) * 260 + row] = stg[u].x;
      wt[(cc + 1) * 260 + row] = stg[u].y;
      wt[(cc + 2) * 260 + row] = stg[u].z;
      wt[(cc + 3) * 260 + row] = stg[u].w;
    }
    __syncthreads();   // wt ready
    if (c0 + 32 < CC) {
      // prefetch next stage; latency hides under the FMA phase below
#pragma unroll
      for (int u = 0; u < 8; u++) {
        int f = t + u * 256;
        int row = (f >> 2) & 255, qq = f & 3, hh = f >> 10;
        stg[u] = *(const float4*)(w2 + (size_t)(j0 + row) * CC + c0 + 32 +
                                  hh * 16 + qq * 4);
      }
    }
#pragma unroll 2
    for (int c4 = 0; c4 < 8; c4++) {
      float hvv[8][4];
#pragma unroll
      for (int i = 0; i < 8; i++) {
        float4 hv = *(const float4*)(h1w + (size_t)i * CC + c0 + c4 * 4);
        hvv[i][0] = hv.x; hvv[i][1] = hv.y; hvv[i][2] = hv.z; hvv[i][3] = hv.w;
      }
#pragma unroll
      for (int r = 0; r < 4; r++) {
        float4 wv4 = *(const float4*)&wt[(c4 * 4 + r) * 260 + jj];
#pragma unroll
        for (int i = 0; i < 8; i++) {
          float h = hvv[i][r];
          acc[i].x += h * wv4.x;
          acc[i].y += h * wv4.y;
          acc[i].z += h * wv4.z;
          acc[i].w += h * wv4.w;
        }
      }
    }
  }

  float4 bv = *(const float4*)(b2 + j0 + jj);
  float s[8], ss[8];
#pragma unroll
  for (int i = 0; i < 8; i++) {
    float4 o;
    o.x = acc[i].x + bv.x; o.y = acc[i].y + bv.y;
    o.z = acc[i].z + bv.z; o.w = acc[i].w + bv.w;
    *(float4*)(h2 + (size_t)(n4 + i) * DOUT + j0 + jj) = o;
    s[i] = o.x + o.y + o.z + o.w;
    ss[i] = o.x * o.x + o.y * o.y + o.z * o.z + o.w * o.w;
  }
#pragma unroll
  for (int off = 32; off; off >>= 1)
#pragma unroll
    for (int i = 0; i < 8; i++) {
      s[i] += __shfl_down(s[i], off);
      ss[i] += __shfl_down(ss[i], off);
    }
  if (lane == 0) {
    float* dst = st_part + (size_t)blockIdx.x * 64;
#pragma unroll
    for (int i = 0; i < 8; i++) {
      dst[n4 + i] = s[i];
      dst[32 + n4 + i] = ss[i];
    }
  }
}

// ---------------- K6: reduce st_part[512][64] -> st[64] ---------------------
__global__ __launch_bounds__(256) void k_stat(const float* __restrict__ st_part,
                                              float* __restrict__ st) {
  int e = blockIdx.x;   // 0..63
  int t = threadIdx.x;
  float s = 0.f;
  for (int p = t; p < 512; p += 256) s += st_part[(size_t)p * 64 + e];
#pragma unroll
  for (int off = 32; off; off >>= 1) s += __shfl_down(s, off);
  __shared__ float ps[4];
  if ((t & 63) == 0) ps[t >> 6] = s;
  __syncthreads();
  if (t == 0) st[e] = ps[0] + ps[1] + ps[2] + ps[3];
}

// ---------------- K7: out = BN(y @ w_out^T) + x, y = LN2(h2)*g2+b2 ----------
__global__ __launch_bounds__(256) void k_out(
    const float* __restrict__ h2, const float* __restrict__ st,
    const float* __restrict__ g2, const float* __restrict__ b2,
    const float* __restrict__ w_out, const float* __restrict__ bn_g,
    const float* __restrict__ bn_b, const float* __restrict__ bn_m,
    const float* __restrict__ bn_v, const float* __restrict__ x,
    float* __restrict__ out) {
  __shared__ float wt[IC * 32];    // [o][Os] 16KB
  __shared__ float yt[16 * 256];   // [oc][l] 16KB
  int t = threadIdx.x;
  int l0 = blockIdx.x * 256;
  int Ob = blockIdx.y * 32;
  int n = blockIdx.z;
  for (int f = t; f < IC * 32; f += 256) {
    int Os = f & 31, o = f >> 5;
    wt[o * 32 + Os] = w_out[(size_t)(Ob + Os) * IC + o];
  }
  float mu = st[n] * (1.f / DOUT);
  float rs = rsqrtf(st[32 + n] * (1.f / DOUT) - mu * mu + EPSF);
  int lane = t & 63, wid = t >> 6;
  int Obase = wid * 8;
  int ll = lane * 4;
  float4 acc[8];
#pragma unroll
  for (int i = 0; i < 8; i++) acc[i] = make_float4(0.f, 0.f, 0.f, 0.f);

  for (int o0 = 0; o0 < IC; o0 += 16) {
    __syncthreads();
#pragma unroll
    for (int u = 0; u < 16; u++) {
      int d = (o0 + u) * LL + l0 + t;
      float yv = (h2[(size_t)n * DOUT + d] - mu) * rs * g2[d] + b2[d];
      yt[u * 256 + t] = yv;
    }
    __syncthreads();
#pragma unroll
    for (int oc = 0; oc < 16; oc++) {
      int o = o0 + oc;
      float4 w0 = *(const float4*)&wt[o * 32 + Obase];
      float4 w1v = *(const float4*)&wt[o * 32 + Obase + 4];
      float4 yv = *(const float4*)&yt[oc * 256 + ll];
#define FMA_O(wc, idx)                                                        \
  acc[idx].x += yv.x * (wc); acc[idx].y += yv.y * (wc);                       \
  acc[idx].z += yv.z * (wc); acc[idx].w += yv.w * (wc);
      FMA_O(w0.x, 0) FMA_O(w0.y, 1) FMA_O(w0.z, 2) FMA_O(w0.w, 3)
      FMA_O(w1v.x, 4) FMA_O(w1v.y, 5) FMA_O(w1v.z, 6) FMA_O(w1v.w, 7)
#undef FMA_O
    }
  }
#pragma unroll
  for (int i = 0; i < 8; i++) {
    int O = Ob + Obase + i;
    float sc = bn_g[O] * rsqrtf(bn_v[O] + EPSF);
    float sh = bn_b[O] - bn_m[O] * sc;
    size_t base = ((size_t)(n * CC + O)) * LL + l0 + ll;
    float4 xv = *(const float4*)(x + base);
    float4 r;
    r.x = acc[i].x * sc + sh + xv.x;
    r.y = acc[i].y * sc + sh + xv.y;
    r.z = acc[i].z * sc + sh + xv.z;
    r.w = acc[i].w * sc + sh + xv.w;
    *(float4*)(out + base) = r;
  }
}

extern "C" void kernel_launch(void* const* d_in, const int* in_sizes, int n_in,
                              void* d_out, int out_size, void* d_ws,
                              size_t ws_size, hipStream_t stream) {
  const float* x = (const float*)d_in[0];
  const float* wq = (const float*)d_in[1];
  const float* wk = (const float*)d_in[2];
  const float* gamma1 = (const float*)d_in[3];
  const float* beta1 = (const float*)d_in[4];
  const float* w1 = (const float*)d_in[5];
  const float* b1 = (const float*)d_in[6];
  const float* w2 = (const float*)d_in[7];
  const float* b2 = (const float*)d_in[8];
  const float* gamma2 = (const float*)d_in[9];
  const float* beta2 = (const float*)d_in[10];
  const float* w_out = (const float*)d_in[11];
  const float* bn_g = (const float*)d_in[12];
  const float* bn_b = (const float*)d_in[13];
  const float* bn_m = (const float*)d_in[14];
  const float* bn_v = (const float*)d_in[15];
  float* outp = (float*)d_out;
  float* ws = (float*)d_ws;

  // ws layout (floats): q(4194304) | k(4194304) | xt(16MB as ushort) |
  //   f(294912) | st(64) | h1(8192) | st_part(512*64); h2 aliases q.
  float* qb = ws;
  float* kb = ws + 4194304;
  ushort* xtb = (ushort*)(ws + 8388608);
  float* fb = ws + 12582912;
  float* stp = ws + 12877824;
  float* h1b = ws + 12877888;
  float* spart = ws + 12886080;
  float* h2b = qb;

  if (ws_size < 12951616ull * sizeof(float)) return;  // fail visibly

  hipMemsetAsync(fb, 0, 294912 * sizeof(float), stream);  // f (attn atomics)
  k_xt<<<dim3(8, 32), 256, 0, stream>>>(x, xtb);
  k_qk<<<dim3(8, 32), 256, 0, stream>>>(xtb, wq, wk, qb, kb);
  k_attn<<<dim3(32, 4, 4), 256, 0, stream>>>(qb, kb, fb);
  k_ln1<<<dim3(32), 256, 0, stream>>>(fb, gamma1, beta1);
  k_ffn1<<<dim3(256, 4), 256, 0, stream>>>(fb, w1, b1, h1b);
  k_ffn2<<<dim3(512), 256, 0, stream>>>(h1b, w2, b2, h2b, spart);
  k_stat<<<dim3(64), 256, 0, stream>>>(spart, stp);
  k_out<<<dim3(4, 8, 32), 256, 0, stream>>>(h2b, stp, gamma2, beta2, w_out,
                                            bn_g, bn_b, bn_m, bn_v, x, outp);
}

// Round 2
// 421.789 us; speedup vs baseline: 1.0413x; 1.0074x over previous
//
#include <hip/hip_runtime.h>

#define NN 32
#define CC 256
#define LL 1024
#define IC 128
#define R2 9
#define DA 9216
#define DOUT 131072
#define EPSF 1e-5f

typedef __attribute__((ext_vector_type(8))) short short8;
typedef __attribute__((ext_vector_type(4))) float f32x4;

__device__ __forceinline__ ushort bf_rne(float f) {
  union { float f; unsigned u; } v;
  v.f = f;
  unsigned u = v.u;
  u += 0x7FFF + ((u >> 16) & 1);
  return (ushort)(u >> 16);
}

// ---------------- K0: xt[n][l][c] bf16 <- x[n][c][l] fp32 -------------------
__global__ __launch_bounds__(256) void k_xt(const float* __restrict__ x,
                                            ushort* __restrict__ xt) {
  int n = blockIdx.y;
  int l = blockIdx.x * 128 + (threadIdx.x & 127);
  int chalf = (threadIdx.x >> 7) * 128;
  const float* xn = x + ((size_t)n * CC) * LL;
  ushort* xr = xt + ((size_t)n * LL + l) * CC + chalf;
#pragma unroll 4
  for (int c4 = 0; c4 < 32; c4++) {
    float a = xn[(size_t)(chalf + c4 * 4 + 0) * LL + l];
    float b = xn[(size_t)(chalf + c4 * 4 + 1) * LL + l];
    float c = xn[(size_t)(chalf + c4 * 4 + 2) * LL + l];
    float d = xn[(size_t)(chalf + c4 * 4 + 3) * LL + l];
    ushort4 o;
    o.x = bf_rne(a); o.y = bf_rne(b); o.z = bf_rne(c); o.w = bf_rne(d);
    *(ushort4*)(xr + c4 * 4) = o;
  }
}

// ---------------- K1: q = wq*x, k = wk*x via bf16 MFMA ----------------------
__global__ __launch_bounds__(256, 1) void k_qk(const ushort* __restrict__ xt,
                                               const float* __restrict__ wq,
                                               const float* __restrict__ wk,
                                               float* __restrict__ q,
                                               float* __restrict__ k) {
  int bx = blockIdx.x;
  int n = blockIdx.y;
  int mt = bx & 1, lt = bx >> 1;
  int l0 = lt * 256;
  int t = threadIdx.x;
  int lane = t & 63, wv = t >> 6;
  int m16 = lane & 15, kg = lane >> 4;
  const float* wrow = mt ? wk : wq;

  short8 a[2][8];
#pragma unroll
  for (int ms = 0; ms < 2; ms++)
#pragma unroll
    for (int kc = 0; kc < 8; kc++) {
      const float* ap =
          wrow + (size_t)(wv * 32 + ms * 16 + m16) * CC + kc * 32 + kg * 8;
      short8 v;
#pragma unroll
      for (int j = 0; j < 8; j++) v[j] = (short)bf_rne(ap[j]);
      a[ms][kc] = v;
    }

  f32x4 acc0[16], acc1[16];
#pragma unroll
  for (int i = 0; i < 16; i++) {
    acc0[i] = (f32x4){0.f, 0.f, 0.f, 0.f};
    acc1[i] = (f32x4){0.f, 0.f, 0.f, 0.f};
  }

  const ushort* xrow = xt + ((size_t)n * LL + l0 + m16) * CC + kg * 8;
#pragma unroll
  for (int kc = 0; kc < 8; kc++) {
#pragma unroll
    for (int ls = 0; ls < 16; ls++) {
      short8 b = *(const short8*)(xrow + (size_t)ls * 16 * CC + kc * 32);
      acc0[ls] =
          __builtin_amdgcn_mfma_f32_16x16x32_bf16(a[0][kc], b, acc0[ls], 0, 0, 0);
      acc1[ls] =
          __builtin_amdgcn_mfma_f32_16x16x32_bf16(a[1][kc], b, acc1[ls], 0, 0, 0);
    }
  }

  float* outp = (mt ? k : q) + (size_t)n * IC * LL;
  int mq = kg * 4;
#pragma unroll
  for (int ls = 0; ls < 16; ls++) {
    int col = l0 + ls * 16 + m16;
#pragma unroll
    for (int r = 0; r < 4; r++) {
      outp[(size_t)(wv * 32 + mq + r) * LL + col] = acc0[ls][r];
      outp[(size_t)(wv * 32 + 16 + mq + r) * LL + col] = acc1[ls][r];
    }
  }
}

// ---------------- K2: local 3x3 attention scores, f2 += 2*(q.k_patch) -------
__global__ __launch_bounds__(256) void k_attn(const float* __restrict__ q,
                                              const float* __restrict__ k,
                                              float* __restrict__ f2) {
  int n = blockIdx.x;
  int c0 = blockIdx.y * 32;
  int l = blockIdx.z * 256 + threadIdx.x;
  int h = l >> 5, w = l & 31;
  const float* qn = q + (size_t)n * IC * LL;
  const float* kn = k + (size_t)n * IC * LL;
  bool val[9];
  int off[9];
#pragma unroll
  for (int i = 0; i < 3; i++)
#pragma unroll
    for (int j = 0; j < 3; j++) {
      int r = i * 3 + j;
      int hh = h + i - 1, ww = w + j - 1;
      val[r] = (hh >= 0 && hh < 32 && ww >= 0 && ww < 32);
      off[r] = hh * 32 + ww;
    }
  float acc[9];
#pragma unroll
  for (int r = 0; r < 9; r++) acc[r] = 0.f;
#pragma unroll 4
  for (int cc = 0; cc < 32; cc++) {
    int c = c0 + cc;
    float qv = qn[c * LL + l];
    const float* kc = kn + c * LL;
#pragma unroll
    for (int r = 0; r < 9; r++) {
      float kv = val[r] ? kc[off[r]] : 0.f;
      acc[r] += qv * kv;
    }
  }
#pragma unroll
  for (int r = 0; r < 9; r++)
    atomicAdd(&f2[(size_t)n * DA + r * LL + l], 2.f * acc[r]);
}

// ---------------- K3: LayerNorm over 9216, in place -------------------------
__global__ __launch_bounds__(256) void k_ln1(float* __restrict__ f2,
                                             const float* __restrict__ g1,
                                             const float* __restrict__ b1) {
  int n = blockIdx.x, t = threadIdx.x;
  float* row = f2 + (size_t)n * DA;
  float4 v[9];
  float s = 0.f, ss = 0.f;
#pragma unroll
  for (int kk = 0; kk < 9; kk++) {
    v[kk] = ((const float4*)row)[t + kk * 256];
    s += v[kk].x + v[kk].y + v[kk].z + v[kk].w;
    ss += v[kk].x * v[kk].x + v[kk].y * v[kk].y + v[kk].z * v[kk].z +
          v[kk].w * v[kk].w;
  }
#pragma unroll
  for (int o = 32; o; o >>= 1) {
    s += __shfl_down(s, o);
    ss += __shfl_down(ss, o);
  }
  __shared__ float ps[4], pss[4], stats[2];
  int wid = t >> 6, lid = t & 63;
  if (lid == 0) { ps[wid] = s; pss[wid] = ss; }
  __syncthreads();
  if (t == 0) {
    float S = ps[0] + ps[1] + ps[2] + ps[3];
    float SS = pss[0] + pss[1] + pss[2] + pss[3];
    float mu = S / DA;
    float var = SS / DA - mu * mu;
    stats[0] = mu;
    stats[1] = rsqrtf(var + EPSF);
  }
  __syncthreads();
  float mu = stats[0], rs = stats[1];
#pragma unroll
  for (int kk = 0; kk < 9; kk++) {
    float4 g = ((const float4*)g1)[t + kk * 256];
    float4 b = ((const float4*)b1)[t + kk * 256];
    float4 o;
    o.x = (v[kk].x - mu) * rs * g.x + b.x;
    o.y = (v[kk].y - mu) * rs * g.y + b.y;
    o.z = (v[kk].z - mu) * rs * g.z + b.z;
    o.w = (v[kk].w - mu) * rs * g.w + b.w;
    ((float4*)row)[t + kk * 256] = o;
  }
}

// ---------------- K4: h1 = relu(fln @ w1^T + b1), n-split x4 ----------------
__global__ __launch_bounds__(256) void k_ffn1(const float* __restrict__ fln,
                                              const float* __restrict__ w1,
                                              const float* __restrict__ b1,
                                              float* __restrict__ h1) {
  int o = blockIdx.x, nsb = blockIdx.y * 8, t = threadIdx.x;
  float acc[8];
#pragma unroll
  for (int i = 0; i < 8; i++) acc[i] = 0.f;
  const float4* w1r = (const float4*)(w1 + (size_t)o * DA);
  for (int kk = 0; kk < 9; kk++) {
    float4 wv = w1r[t + kk * 256];
#pragma unroll
    for (int i = 0; i < 8; i++) {
      float4 fv = ((const float4*)(fln + (size_t)(nsb + i) * DA))[t + kk * 256];
      acc[i] += wv.x * fv.x + wv.y * fv.y + wv.z * fv.z + wv.w * fv.w;
    }
  }
#pragma unroll
  for (int i = 0; i < 8; i++)
#pragma unroll
    for (int s = 32; s; s >>= 1) acc[i] += __shfl_down(acc[i], s);
  __shared__ float part[4][8];
  int wid = t >> 6, lid = t & 63;
  if (lid == 0) {
#pragma unroll
    for (int i = 0; i < 8; i++) part[wid][i] = acc[i];
  }
  __syncthreads();
  if (t < 8) {
    float sum = part[0][t] + part[1][t] + part[2][t] + part[3][t] + b1[o];
    h1[(size_t)(nsb + t) * CC + o] = fmaxf(sum, 0.f);
  }
}

// ---------------- K5: h2 = h1 @ w2^T + b2, per-block LN2 partials -----------
// R2: grid 1024 (j-tiles of 128), block 256 = 4 waves -> 4 blocks/CU,
// 16 waves/CU (50% occupancy). Wave w owns n rows [8w,8w+8); lane>>5 picks
// the 4-row half; lane&31 owns j quad. Thread tile 4n x 4j.
// wt[32][132]: +4 pad keeps 16B-aligned b128 reads, free 2-way write conflict.
// h1 read direct from global (L1/L2-resident, 2 addrs/wave). T14 prefetch.
__global__ __launch_bounds__(256, 4) void k_ffn2(const float* __restrict__ h1,
                                                 const float* __restrict__ w2,
                                                 const float* __restrict__ b2,
                                                 float* __restrict__ h2,
                                                 float* __restrict__ st_part) {
  __shared__ float wt[32 * 132];   // 16.9 KB
  int t = threadIdx.x;
  int j0 = blockIdx.x * 128;
  int lane = t & 63, wv = t >> 6;
  int ng = lane >> 5;
  int jl = lane & 31;
  int n4 = wv * 8 + ng * 4;
  int jj = jl * 4;
  const float* h1w = h1 + (size_t)n4 * CC;

  float4 acc[4];
#pragma unroll
  for (int i = 0; i < 4; i++) acc[i] = make_float4(0.f, 0.f, 0.f, 0.f);

  // staging geometry: f = t + (u&1)*256 in [0,512); row = f>>2 (0..127),
  // qq = f&3; c-offset = (u>>1)*16 + qq*4. 4 lanes/row -> 64B-coalesced.
  float4 stg[4];
#pragma unroll
  for (int u = 0; u < 4; u++) {
    int f = t + (u & 1) * 256;
    int row = f >> 2, qq = f & 3;
    int coff = (u >> 1) * 16 + qq * 4;
    stg[u] = *(const float4*)(w2 + (size_t)(j0 + row) * CC + coff);
  }

  for (int c0 = 0; c0 < CC; c0 += 32) {
    __syncthreads();   // prev compute done reading wt
#pragma unroll
    for (int u = 0; u < 4; u++) {
      int f = t + (u & 1) * 256;
      int row = f >> 2, qq = f & 3;
      int cc = (u >> 1) * 16 + qq * 4;
      wt[(cc + 0) * 132 + row] = stg[u].x;
      wt[(cc + 1) * 132 + row] = stg[u].y;
      wt[(cc + 2) * 132 + row] = stg[u].z;
      wt[(cc + 3) * 132 + row] = stg[u].w;
    }
    __syncthreads();   // wt ready
    if (c0 + 32 < CC) {
      // prefetch next stage; latency hides under the FMA phase below
#pragma unroll
      for (int u = 0; u < 4; u++) {
        int f = t + (u & 1) * 256;
        int row = f >> 2, qq = f & 3;
        int coff = (u >> 1) * 16 + qq * 4;
        stg[u] = *(const float4*)(w2 + (size_t)(j0 + row) * CC + c0 + 32 + coff);
      }
    }
#pragma unroll 2
    for (int c4 = 0; c4 < 8; c4++) {
      float hvv[4][4];
#pragma unroll
      for (int i = 0; i < 4; i++) {
        float4 hv = *(const float4*)(h1w + (size_t)i * CC + c0 + c4 * 4);
        hvv[i][0] = hv.x; hvv[i][1] = hv.y; hvv[i][2] = hv.z; hvv[i][3] = hv.w;
      }
#pragma unroll
      for (int r = 0; r < 4; r++) {
        float4 wv4 = *(const float4*)&wt[(c4 * 4 + r) * 132 + jj];
#pragma unroll
        for (int i = 0; i < 4; i++) {
          float h = hvv[i][r];
          acc[i].x += h * wv4.x;
          acc[i].y += h * wv4.y;
          acc[i].z += h * wv4.z;
          acc[i].w += h * wv4.w;
        }
      }
    }
  }

  float4 bv = *(const float4*)(b2 + j0 + jj);
  float s[4], ss[4];
#pragma unroll
  for (int i = 0; i < 4; i++) {
    float4 o;
    o.x = acc[i].x + bv.x; o.y = acc[i].y + bv.y;
    o.z = acc[i].z + bv.z; o.w = acc[i].w + bv.w;
    *(float4*)(h2 + (size_t)(n4 + i) * DOUT + j0 + jj) = o;
    s[i] = o.x + o.y + o.z + o.w;
    ss[i] = o.x * o.x + o.y * o.y + o.z * o.z + o.w * o.w;
  }
#pragma unroll
  for (int off = 16; off; off >>= 1)
#pragma unroll
    for (int i = 0; i < 4; i++) {
      s[i] += __shfl_down(s[i], off, 32);
      ss[i] += __shfl_down(ss[i], off, 32);
    }
  if (jl == 0) {
    float* dst = st_part + (size_t)blockIdx.x * 64;
#pragma unroll
    for (int i = 0; i < 4; i++) {
      dst[n4 + i] = s[i];
      dst[32 + n4 + i] = ss[i];
    }
  }
}

// ---------------- K6: reduce st_part[1024][64] -> st[64] --------------------
__global__ __launch_bounds__(256) void k_stat(const float* __restrict__ st_part,
                                              float* __restrict__ st) {
  int e = blockIdx.x;   // 0..63
  int t = threadIdx.x;
  float s = 0.f;
  for (int p = t; p < 1024; p += 256) s += st_part[(size_t)p * 64 + e];
#pragma unroll
  for (int off = 32; off; off >>= 1) s += __shfl_down(s, off);
  __shared__ float ps[4];
  if ((t & 63) == 0) ps[t >> 6] = s;
  __syncthreads();
  if (t == 0) st[e] = ps[0] + ps[1] + ps[2] + ps[3];
}

// ---------------- K7: out = BN(y @ w_out^T) + x, y = LN2(h2)*g2+b2 ----------
__global__ __launch_bounds__(256) void k_out(
    const float* __restrict__ h2, const float* __restrict__ st,
    const float* __restrict__ g2, const float* __restrict__ b2,
    const float* __restrict__ w_out, const float* __restrict__ bn_g,
    const float* __restrict__ bn_b, const float* __restrict__ bn_m,
    const float* __restrict__ bn_v, const float* __restrict__ x,
    float* __restrict__ out) {
  __shared__ float wt[IC * 32];    // [o][Os] 16KB
  __shared__ float yt[16 * 256];   // [oc][l] 16KB
  int t = threadIdx.x;
  int l0 = blockIdx.x * 256;
  int Ob = blockIdx.y * 32;
  int n = blockIdx.z;
  for (int f = t; f < IC * 32; f += 256) {
    int Os = f & 31, o = f >> 5;
    wt[o * 32 + Os] = w_out[(size_t)(Ob + Os) * IC + o];
  }
  float mu = st[n] * (1.f / DOUT);
  float rs = rsqrtf(st[32 + n] * (1.f / DOUT) - mu * mu + EPSF);
  int lane = t & 63, wid = t >> 6;
  int Obase = wid * 8;
  int ll = lane * 4;
  float4 acc[8];
#pragma unroll
  for (int i = 0; i < 8; i++) acc[i] = make_float4(0.f, 0.f, 0.f, 0.f);

  for (int o0 = 0; o0 < IC; o0 += 16) {
    __syncthreads();
#pragma unroll
    for (int u = 0; u < 16; u++) {
      int d = (o0 + u) * LL + l0 + t;
      float yv = (h2[(size_t)n * DOUT + d] - mu) * rs * g2[d] + b2[d];
      yt[u * 256 + t] = yv;
    }
    __syncthreads();
#pragma unroll
    for (int oc = 0; oc < 16; oc++) {
      int o = o0 + oc;
      float4 w0 = *(const float4*)&wt[o * 32 + Obase];
      float4 w1v = *(const float4*)&wt[o * 32 + Obase + 4];
      float4 yv = *(const float4*)&yt[oc * 256 + ll];
#define FMA_O(wc, idx)                                                        \
  acc[idx].x += yv.x * (wc); acc[idx].y += yv.y * (wc);                       \
  acc[idx].z += yv.z * (wc); acc[idx].w += yv.w * (wc);
      FMA_O(w0.x, 0) FMA_O(w0.y, 1) FMA_O(w0.z, 2) FMA_O(w0.w, 3)
      FMA_O(w1v.x, 4) FMA_O(w1v.y, 5) FMA_O(w1v.z, 6) FMA_O(w1v.w, 7)
#undef FMA_O
    }
  }
#pragma unroll
  for (int i = 0; i < 8; i++) {
    int O = Ob + Obase + i;
    float sc = bn_g[O] * rsqrtf(bn_v[O] + EPSF);
    float sh = bn_b[O] - bn_m[O] * sc;
    size_t base = ((size_t)(n * CC + O)) * LL + l0 + ll;
    float4 xv = *(const float4*)(x + base);
    float4 r;
    r.x = acc[i].x * sc + sh + xv.x;
    r.y = acc[i].y * sc + sh + xv.y;
    r.z = acc[i].z * sc + sh + xv.z;
    r.w = acc[i].w * sc + sh + xv.w;
    *(float4*)(out + base) = r;
  }
}

extern "C" void kernel_launch(void* const* d_in, const int* in_sizes, int n_in,
                              void* d_out, int out_size, void* d_ws,
                              size_t ws_size, hipStream_t stream) {
  const float* x = (const float*)d_in[0];
  const float* wq = (const float*)d_in[1];
  const float* wk = (const float*)d_in[2];
  const float* gamma1 = (const float*)d_in[3];
  const float* beta1 = (const float*)d_in[4];
  const float* w1 = (const float*)d_in[5];
  const float* b1 = (const float*)d_in[6];
  const float* w2 = (const float*)d_in[7];
  const float* b2 = (const float*)d_in[8];
  const float* gamma2 = (const float*)d_in[9];
  const float* beta2 = (const float*)d_in[10];
  const float* w_out = (const float*)d_in[11];
  const float* bn_g = (const float*)d_in[12];
  const float* bn_b = (const float*)d_in[13];
  const float* bn_m = (const float*)d_in[14];
  const float* bn_v = (const float*)d_in[15];
  float* outp = (float*)d_out;
  float* ws = (float*)d_ws;

  // ws layout (floats): q(4194304) | k(4194304) | xt(16MB as ushort) |
  //   f(294912) | st(64) | h1(8192) | st_part(1024*64); h2 aliases q.
  float* qb = ws;
  float* kb = ws + 4194304;
  ushort* xtb = (ushort*)(ws + 8388608);
  float* fb = ws + 12582912;
  float* stp = ws + 12877824;
  float* h1b = ws + 12877888;
  float* spart = ws + 12886080;
  float* h2b = qb;

  if (ws_size < 12951616ull * sizeof(float)) return;  // fail visibly

  hipMemsetAsync(fb, 0, 294912 * sizeof(float), stream);  // f (attn atomics)
  k_xt<<<dim3(8, 32), 256, 0, stream>>>(x, xtb);
  k_qk<<<dim3(8, 32), 256, 0, stream>>>(xtb, wq, wk, qb, kb);
  k_attn<<<dim3(32, 4, 4), 256, 0, stream>>>(qb, kb, fb);
  k_ln1<<<dim3(32), 256, 0, stream>>>(fb, gamma1, beta1);
  k_ffn1<<<dim3(256, 4), 256, 0, stream>>>(fb, w1, b1, h1b);
  k_ffn2<<<dim3(1024), 256, 0, stream>>>(h1b, w2, b2, h2b, spart);
  k_stat<<<dim3(64), 256, 0, stream>>>(spart, stp);
  k_out<<<dim3(4, 8, 32), 256, 0, stream>>>(h2b, stp, gamma2, beta2, w_out,
                                            bn_g, bn_b, bn_m, bn_v, x, outp);
}

// Round 3
// 411.869 us; speedup vs baseline: 1.0664x; 1.0241x over previous
//
#include <hip/hip_runtime.h>

#define NN 32
#define CC 256
#define LL 1024
#define IC 128
#define R2 9
#define DA 9216
#define DOUT 131072
#define EPSF 1e-5f

typedef __attribute__((ext_vector_type(8))) short short8;
typedef __attribute__((ext_vector_type(4))) float f32x4;

__device__ __forceinline__ ushort bf_rne(float f) {
  union { float f; unsigned u; } v;
  v.f = f;
  unsigned u = v.u;
  u += 0x7FFF + ((u >> 16) & 1);
  return (ushort)(u >> 16);
}

// ---------------- K0: xt[n][l][c] bf16 <- x[n][c][l] fp32 -------------------
__global__ __launch_bounds__(256) void k_xt(const float* __restrict__ x,
                                            ushort* __restrict__ xt) {
  int n = blockIdx.y;
  int l = blockIdx.x * 128 + (threadIdx.x & 127);
  int chalf = (threadIdx.x >> 7) * 128;
  const float* xn = x + ((size_t)n * CC) * LL;
  ushort* xr = xt + ((size_t)n * LL + l) * CC + chalf;
#pragma unroll 4
  for (int c4 = 0; c4 < 32; c4++) {
    float a = xn[(size_t)(chalf + c4 * 4 + 0) * LL + l];
    float b = xn[(size_t)(chalf + c4 * 4 + 1) * LL + l];
    float c = xn[(size_t)(chalf + c4 * 4 + 2) * LL + l];
    float d = xn[(size_t)(chalf + c4 * 4 + 3) * LL + l];
    ushort4 o;
    o.x = bf_rne(a); o.y = bf_rne(b); o.z = bf_rne(c); o.w = bf_rne(d);
    *(ushort4*)(xr + c4 * 4) = o;
  }
}

// ---------------- K1: q = wq*x, k = wk*x via bf16 MFMA ----------------------
__global__ __launch_bounds__(256, 1) void k_qk(const ushort* __restrict__ xt,
                                               const float* __restrict__ wq,
                                               const float* __restrict__ wk,
                                               float* __restrict__ q,
                                               float* __restrict__ k) {
  int bx = blockIdx.x;
  int n = blockIdx.y;
  int mt = bx & 1, lt = bx >> 1;
  int l0 = lt * 256;
  int t = threadIdx.x;
  int lane = t & 63, wv = t >> 6;
  int m16 = lane & 15, kg = lane >> 4;
  const float* wrow = mt ? wk : wq;

  short8 a[2][8];
#pragma unroll
  for (int ms = 0; ms < 2; ms++)
#pragma unroll
    for (int kc = 0; kc < 8; kc++) {
      const float* ap =
          wrow + (size_t)(wv * 32 + ms * 16 + m16) * CC + kc * 32 + kg * 8;
      short8 v;
#pragma unroll
      for (int j = 0; j < 8; j++) v[j] = (short)bf_rne(ap[j]);
      a[ms][kc] = v;
    }

  f32x4 acc0[16], acc1[16];
#pragma unroll
  for (int i = 0; i < 16; i++) {
    acc0[i] = (f32x4){0.f, 0.f, 0.f, 0.f};
    acc1[i] = (f32x4){0.f, 0.f, 0.f, 0.f};
  }

  const ushort* xrow = xt + ((size_t)n * LL + l0 + m16) * CC + kg * 8;
#pragma unroll
  for (int kc = 0; kc < 8; kc++) {
#pragma unroll
    for (int ls = 0; ls < 16; ls++) {
      short8 b = *(const short8*)(xrow + (size_t)ls * 16 * CC + kc * 32);
      acc0[ls] =
          __builtin_amdgcn_mfma_f32_16x16x32_bf16(a[0][kc], b, acc0[ls], 0, 0, 0);
      acc1[ls] =
          __builtin_amdgcn_mfma_f32_16x16x32_bf16(a[1][kc], b, acc1[ls], 0, 0, 0);
    }
  }

  float* outp = (mt ? k : q) + (size_t)n * IC * LL;
  int mq = kg * 4;
#pragma unroll
  for (int ls = 0; ls < 16; ls++) {
    int col = l0 + ls * 16 + m16;
#pragma unroll
    for (int r = 0; r < 4; r++) {
      outp[(size_t)(wv * 32 + mq + r) * LL + col] = acc0[ls][r];
      outp[(size_t)(wv * 32 + 16 + mq + r) * LL + col] = acc1[ls][r];
    }
  }
}

// ---------------- K2: local 3x3 attention scores, f2 += 2*(q.k_patch) -------
__global__ __launch_bounds__(256) void k_attn(const float* __restrict__ q,
                                              const float* __restrict__ k,
                                              float* __restrict__ f2) {
  int n = blockIdx.x;
  int c0 = blockIdx.y * 32;
  int l = blockIdx.z * 256 + threadIdx.x;
  int h = l >> 5, w = l & 31;
  const float* qn = q + (size_t)n * IC * LL;
  const float* kn = k + (size_t)n * IC * LL;
  bool val[9];
  int off[9];
#pragma unroll
  for (int i = 0; i < 3; i++)
#pragma unroll
    for (int j = 0; j < 3; j++) {
      int r = i * 3 + j;
      int hh = h + i - 1, ww = w + j - 1;
      val[r] = (hh >= 0 && hh < 32 && ww >= 0 && ww < 32);
      off[r] = hh * 32 + ww;
    }
  float acc[9];
#pragma unroll
  for (int r = 0; r < 9; r++) acc[r] = 0.f;
#pragma unroll 4
  for (int cc = 0; cc < 32; cc++) {
    int c = c0 + cc;
    float qv = qn[c * LL + l];
    const float* kc = kn + c * LL;
#pragma unroll
    for (int r = 0; r < 9; r++) {
      float kv = val[r] ? kc[off[r]] : 0.f;
      acc[r] += qv * kv;
    }
  }
#pragma unroll
  for (int r = 0; r < 9; r++)
    atomicAdd(&f2[(size_t)n * DA + r * LL + l], 2.f * acc[r]);
}

// ---------------- K3: LayerNorm over 9216, in place -------------------------
__global__ __launch_bounds__(256) void k_ln1(float* __restrict__ f2,
                                             const float* __restrict__ g1,
                                             const float* __restrict__ b1) {
  int n = blockIdx.x, t = threadIdx.x;
  float* row = f2 + (size_t)n * DA;
  float4 v[9];
  float s = 0.f, ss = 0.f;
#pragma unroll
  for (int kk = 0; kk < 9; kk++) {
    v[kk] = ((const float4*)row)[t + kk * 256];
    s += v[kk].x + v[kk].y + v[kk].z + v[kk].w;
    ss += v[kk].x * v[kk].x + v[kk].y * v[kk].y + v[kk].z * v[kk].z +
          v[kk].w * v[kk].w;
  }
#pragma unroll
  for (int o = 32; o; o >>= 1) {
    s += __shfl_down(s, o);
    ss += __shfl_down(ss, o);
  }
  __shared__ float ps[4], pss[4], stats[2];
  int wid = t >> 6, lid = t & 63;
  if (lid == 0) { ps[wid] = s; pss[wid] = ss; }
  __syncthreads();
  if (t == 0) {
    float S = ps[0] + ps[1] + ps[2] + ps[3];
    float SS = pss[0] + pss[1] + pss[2] + pss[3];
    float mu = S / DA;
    float var = SS / DA - mu * mu;
    stats[0] = mu;
    stats[1] = rsqrtf(var + EPSF);
  }
  __syncthreads();
  float mu = stats[0], rs = stats[1];
#pragma unroll
  for (int kk = 0; kk < 9; kk++) {
    float4 g = ((const float4*)g1)[t + kk * 256];
    float4 b = ((const float4*)b1)[t + kk * 256];
    float4 o;
    o.x = (v[kk].x - mu) * rs * g.x + b.x;
    o.y = (v[kk].y - mu) * rs * g.y + b.y;
    o.z = (v[kk].z - mu) * rs * g.z + b.z;
    o.w = (v[kk].w - mu) * rs * g.w + b.w;
    ((float4*)row)[t + kk * 256] = o;
  }
}

// ---------------- K4: h1 = relu(fln @ w1^T + b1) -> bf16, n-split x4 --------
__global__ __launch_bounds__(256) void k_ffn1(const float* __restrict__ fln,
                                              const float* __restrict__ w1,
                                              const float* __restrict__ b1,
                                              ushort* __restrict__ h1bf) {
  int o = blockIdx.x, nsb = blockIdx.y * 8, t = threadIdx.x;
  float acc[8];
#pragma unroll
  for (int i = 0; i < 8; i++) acc[i] = 0.f;
  const float4* w1r = (const float4*)(w1 + (size_t)o * DA);
  for (int kk = 0; kk < 9; kk++) {
    float4 wv = w1r[t + kk * 256];
#pragma unroll
    for (int i = 0; i < 8; i++) {
      float4 fv = ((const float4*)(fln + (size_t)(nsb + i) * DA))[t + kk * 256];
      acc[i] += wv.x * fv.x + wv.y * fv.y + wv.z * fv.z + wv.w * fv.w;
    }
  }
#pragma unroll
  for (int i = 0; i < 8; i++)
#pragma unroll
    for (int s = 32; s; s >>= 1) acc[i] += __shfl_down(acc[i], s);
  __shared__ float part[4][8];
  int wid = t >> 6, lid = t & 63;
  if (lid == 0) {
#pragma unroll
    for (int i = 0; i < 8; i++) part[wid][i] = acc[i];
  }
  __syncthreads();
  if (t < 8) {
    float sum = part[0][t] + part[1][t] + part[2][t] + part[3][t] + b1[o];
    h1bf[(size_t)(nsb + t) * CC + o] = bf_rne(fmaxf(sum, 0.f));
  }
}

// ---------------- K5: h2 = h1 @ w2^T + b2 via bf16 MFMA ---------------------
// R3: pure streaming kernel. Grid 512 (j-tiles of 256), block 256 = 4 waves,
// launch_bounds(256,3) -> all 512 blocks co-resident (3 blocks/CU), no tail.
// Wave owns full M=32 x 64 j-cols: 2 m-frags x 4 n-frags, K=256 = 8 kc-steps,
// 64 MFMA (16x16x32, layout proven in k_qk). w2 fp32 read direct from global
// (full 128B-line use: wave covers 32 rows x 128B per kc), cvt to bf16 in-reg.
// No LDS tiles, no per-phase barriers -> no barrier-drain, no dependent-load
// stall into FMAs. LN2 partials via width-16 shuffle + LDS atomics.
__global__ __launch_bounds__(256, 3) void k_ffn2(
    const ushort* __restrict__ h1bf, const float* __restrict__ w2,
    const float* __restrict__ b2, float* __restrict__ h2,
    float* __restrict__ st_part) {
  __shared__ float bs[64];
  int t = threadIdx.x;
  int lane = t & 63, wv = t >> 6;
  int m16 = lane & 15, kg = lane >> 4;
  int j0 = blockIdx.x * 256 + wv * 64;
  if (t < 64) bs[t] = 0.f;

  // A fragments: rows m*16+m16 of h1bf, k = kc*32 + kg*8 .. +8
  short8 a[2][8];
#pragma unroll
  for (int m = 0; m < 2; m++)
#pragma unroll
    for (int kc = 0; kc < 8; kc++)
      a[m][kc] = *(const short8*)(h1bf + (size_t)(m * 16 + m16) * CC +
                                  kc * 32 + kg * 8);

  f32x4 acc[2][4];
#pragma unroll
  for (int m = 0; m < 2; m++)
#pragma unroll
    for (int n = 0; n < 4; n++) acc[m][n] = (f32x4){0.f, 0.f, 0.f, 0.f};

  int j[4];
#pragma unroll
  for (int n = 0; n < 4; n++) j[n] = j0 + n * 16 + m16;

#pragma unroll
  for (int kc = 0; kc < 8; kc++) {
    short8 bfrag[4];
#pragma unroll
    for (int n = 0; n < 4; n++) {
      const float* src = w2 + (size_t)j[n] * CC + kc * 32 + kg * 8;
      float4 lo = *(const float4*)src;
      float4 hi = *(const float4*)(src + 4);
      union { short8 s; ushort u[8]; } cv;
      cv.u[0] = bf_rne(lo.x); cv.u[1] = bf_rne(lo.y);
      cv.u[2] = bf_rne(lo.z); cv.u[3] = bf_rne(lo.w);
      cv.u[4] = bf_rne(hi.x); cv.u[5] = bf_rne(hi.y);
      cv.u[6] = bf_rne(hi.z); cv.u[7] = bf_rne(hi.w);
      bfrag[n] = cv.s;
    }
#pragma unroll
    for (int m = 0; m < 2; m++)
#pragma unroll
      for (int n = 0; n < 4; n++)
        acc[m][n] = __builtin_amdgcn_mfma_f32_16x16x32_bf16(a[m][kc], bfrag[n],
                                                            acc[m][n], 0, 0, 0);
  }
  __syncthreads();   // bs zero-init visible before atomics below

  float b2v[4];
#pragma unroll
  for (int n = 0; n < 4; n++) b2v[n] = b2[j[n]];

  // store h2 (+bias) and accumulate per-row partial sums for LN2
  float s8[2][4], q8[2][4];
#pragma unroll
  for (int m = 0; m < 2; m++)
#pragma unroll
    for (int r = 0; r < 4; r++) { s8[m][r] = 0.f; q8[m][r] = 0.f; }
#pragma unroll
  for (int m = 0; m < 2; m++)
#pragma unroll
    for (int n = 0; n < 4; n++) {
#pragma unroll
      for (int r = 0; r < 4; r++) {
        float v = acc[m][n][r] + b2v[n];
        int row = m * 16 + kg * 4 + r;
        h2[(size_t)row * DOUT + j[n]] = v;
        s8[m][r] += v;
        q8[m][r] += v * v;
      }
    }
  // reduce over the 16 j-lanes (width-16 shuffle)
#pragma unroll
  for (int off = 8; off; off >>= 1)
#pragma unroll
    for (int m = 0; m < 2; m++)
#pragma unroll
      for (int r = 0; r < 4; r++) {
        s8[m][r] += __shfl_down(s8[m][r], off, 16);
        q8[m][r] += __shfl_down(q8[m][r], off, 16);
      }
  if (m16 == 0) {
#pragma unroll
    for (int m = 0; m < 2; m++)
#pragma unroll
      for (int r = 0; r < 4; r++) {
        int row = m * 16 + kg * 4 + r;
        atomicAdd(&bs[row], s8[m][r]);
        atomicAdd(&bs[32 + row], q8[m][r]);
      }
  }
  __syncthreads();
  if (t < 64) st_part[(size_t)blockIdx.x * 64 + t] = bs[t];
}

// ---------------- K6: reduce st_part[512][64] -> st[64] ---------------------
__global__ __launch_bounds__(256) void k_stat(const float* __restrict__ st_part,
                                              float* __restrict__ st) {
  int e = blockIdx.x;   // 0..63
  int t = threadIdx.x;
  float s = 0.f;
  for (int p = t; p < 512; p += 256) s += st_part[(size_t)p * 64 + e];
#pragma unroll
  for (int off = 32; off; off >>= 1) s += __shfl_down(s, off);
  __shared__ float ps[4];
  if ((t & 63) == 0) ps[t >> 6] = s;
  __syncthreads();
  if (t == 0) st[e] = ps[0] + ps[1] + ps[2] + ps[3];
}

// ---------------- K7: out = BN(y @ w_out^T) + x, y = LN2(h2)*g2+b2 ----------
__global__ __launch_bounds__(256) void k_out(
    const float* __restrict__ h2, const float* __restrict__ st,
    const float* __restrict__ g2, const float* __restrict__ b2,
    const float* __restrict__ w_out, const float* __restrict__ bn_g,
    const float* __restrict__ bn_b, const float* __restrict__ bn_m,
    const float* __restrict__ bn_v, const float* __restrict__ x,
    float* __restrict__ out) {
  __shared__ float wt[IC * 32];    // [o][Os] 16KB
  __shared__ float yt[16 * 256];   // [oc][l] 16KB
  int t = threadIdx.x;
  int l0 = blockIdx.x * 256;
  int Ob = blockIdx.y * 32;
  int n = blockIdx.z;
  for (int f = t; f < IC * 32; f += 256) {
    int Os = f & 31, o = f >> 5;
    wt[o * 32 + Os] = w_out[(size_t)(Ob + Os) * IC + o];
  }
  float mu = st[n] * (1.f / DOUT);
  float rs = rsqrtf(st[32 + n] * (1.f / DOUT) - mu * mu + EPSF);
  int lane = t & 63, wid = t >> 6;
  int Obase = wid * 8;
  int ll = lane * 4;
  float4 acc[8];
#pragma unroll
  for (int i = 0; i < 8; i++) acc[i] = make_float4(0.f, 0.f, 0.f, 0.f);

  for (int o0 = 0; o0 < IC; o0 += 16) {
    __syncthreads();
#pragma unroll
    for (int u = 0; u < 16; u++) {
      int d = (o0 + u) * LL + l0 + t;
      float yv = (h2[(size_t)n * DOUT + d] - mu) * rs * g2[d] + b2[d];
      yt[u * 256 + t] = yv;
    }
    __syncthreads();
#pragma unroll
    for (int oc = 0; oc < 16; oc++) {
      int o = o0 + oc;
      float4 w0 = *(const float4*)&wt[o * 32 + Obase];
      float4 w1v = *(const float4*)&wt[o * 32 + Obase + 4];
      float4 yv = *(const float4*)&yt[oc * 256 + ll];
#define FMA_O(wc, idx)                                                        \
  acc[idx].x += yv.x * (wc); acc[idx].y += yv.y * (wc);                       \
  acc[idx].z += yv.z * (wc); acc[idx].w += yv.w * (wc);
      FMA_O(w0.x, 0) FMA_O(w0.y, 1) FMA_O(w0.z, 2) FMA_O(w0.w, 3)
      FMA_O(w1v.x, 4) FMA_O(w1v.y, 5) FMA_O(w1v.z, 6) FMA_O(w1v.w, 7)
#undef FMA_O
    }
  }
#pragma unroll
  for (int i = 0; i < 8; i++) {
    int O = Ob + Obase + i;
    float sc = bn_g[O] * rsqrtf(bn_v[O] + EPSF);
    float sh = bn_b[O] - bn_m[O] * sc;
    size_t base = ((size_t)(n * CC + O)) * LL + l0 + ll;
    float4 xv = *(const float4*)(x + base);
    float4 r;
    r.x = acc[i].x * sc + sh + xv.x;
    r.y = acc[i].y * sc + sh + xv.y;
    r.z = acc[i].z * sc + sh + xv.z;
    r.w = acc[i].w * sc + sh + xv.w;
    *(float4*)(out + base) = r;
  }
}

extern "C" void kernel_launch(void* const* d_in, const int* in_sizes, int n_in,
                              void* d_out, int out_size, void* d_ws,
                              size_t ws_size, hipStream_t stream) {
  const float* x = (const float*)d_in[0];
  const float* wq = (const float*)d_in[1];
  const float* wk = (const float*)d_in[2];
  const float* gamma1 = (const float*)d_in[3];
  const float* beta1 = (const float*)d_in[4];
  const float* w1 = (const float*)d_in[5];
  const float* b1 = (const float*)d_in[6];
  const float* w2 = (const float*)d_in[7];
  const float* b2 = (const float*)d_in[8];
  const float* gamma2 = (const float*)d_in[9];
  const float* beta2 = (const float*)d_in[10];
  const float* w_out = (const float*)d_in[11];
  const float* bn_g = (const float*)d_in[12];
  const float* bn_b = (const float*)d_in[13];
  const float* bn_m = (const float*)d_in[14];
  const float* bn_v = (const float*)d_in[15];
  float* outp = (float*)d_out;
  float* ws = (float*)d_ws;

  // ws layout (floats): q(4194304) | k(4194304) | xt(16MB as ushort) |
  //   f(294912) | st(64) | h1bf(16KB as ushort) | st_part(512*64);
  //   h2 aliases q.
  float* qb = ws;
  float* kb = ws + 4194304;
  ushort* xtb = (ushort*)(ws + 8388608);
  float* fb = ws + 12582912;
  float* stp = ws + 12877824;
  ushort* h1bfb = (ushort*)(ws + 12877888);
  float* spart = ws + 12886080;
  float* h2b = qb;

  if (ws_size < 12951616ull * sizeof(float)) return;  // fail visibly

  hipMemsetAsync(fb, 0, 294912 * sizeof(float), stream);  // f (attn atomics)
  k_xt<<<dim3(8, 32), 256, 0, stream>>>(x, xtb);
  k_qk<<<dim3(8, 32), 256, 0, stream>>>(xtb, wq, wk, qb, kb);
  k_attn<<<dim3(32, 4, 4), 256, 0, stream>>>(qb, kb, fb);
  k_ln1<<<dim3(32), 256, 0, stream>>>(fb, gamma1, beta1);
  k_ffn1<<<dim3(256, 4), 256, 0, stream>>>(fb, w1, b1, h1bfb);
  k_ffn2<<<dim3(512), 256, 0, stream>>>(h1bfb, w2, b2, h2b, spart);
  k_stat<<<dim3(64), 256, 0, stream>>>(spart, stp);
  k_out<<<dim3(4, 8, 32), 256, 0, stream>>>(h2b, stp, gamma2, beta2, w_out,
                                            bn_g, bn_b, bn_m, bn_v, x, outp);
}

// Round 4
// 333.519 us; speedup vs baseline: 1.3170x; 1.2349x over previous
//
#include <hip/hip_runtime.h>

#define NN 32
#define CC 256
#define LL 1024
#define IC 128
#define DA 9216
#define DOUT 131072
#define EPSF 1e-5f

typedef __attribute__((ext_vector_type(8))) short short8;
typedef __attribute__((ext_vector_type(4))) float f32x4;

__device__ __forceinline__ ushort bf_rne(float f) {
  union { float f; unsigned u; } v;
  v.f = f;
  unsigned u = v.u;
  u += 0x7FFF + ((u >> 16) & 1);
  return (ushort)(u >> 16);
}

// ---------------- K_wcvt: wq|wk -> wqkbf, w_out -> wobf (bf16) --------------
__global__ __launch_bounds__(256) void k_wcvt(const float* __restrict__ wq,
                                              const float* __restrict__ wk,
                                              const float* __restrict__ wo,
                                              ushort* __restrict__ wqkbf,
                                              ushort* __restrict__ wobf) {
  int idx = (blockIdx.x * 256 + threadIdx.x) * 4;  // grid 96 -> 98304 elems
  float4 v;
  if (idx < 32768) v = *(const float4*)(wq + idx);
  else if (idx < 65536) v = *(const float4*)(wk + idx - 32768);
  else v = *(const float4*)(wo + idx - 65536);
  ushort4 o;
  o.x = bf_rne(v.x); o.y = bf_rne(v.y); o.z = bf_rne(v.z); o.w = bf_rne(v.w);
  if (idx < 65536) *(ushort4*)(wqkbf + idx) = o;
  else *(ushort4*)(wobf + idx - 65536) = o;
}

// ---------------- K_qkx: fused transpose + q/k MFMA -------------------------
// grid (16 l-tiles of 64, 32 n), 256 thr = 4 waves. LDS x-tile bf16 [l][264]
// (stride 264: 528B = 4 mod 32 banks -> minimal-conflict b128 write, 2-way
// read). Each wave: o-block wv*32, computes BOTH q and k (B-frag reused 4x).
__global__ __launch_bounds__(256, 4) void k_qkx(const float* __restrict__ x,
                                                const ushort* __restrict__ wqkbf,
                                                float* __restrict__ q,
                                                float* __restrict__ k) {
  __shared__ ushort xl[64 * 264];  // 33.8 KB
  int t = threadIdx.x;
  int n = blockIdx.y;
  int l0 = blockIdx.x * 64;
  int lane = t & 63, wv = t >> 6;
  int m16 = lane & 15, kg = lane >> 4;

  // stage x[c][l0..l0+64) -> xl[l][c] bf16, 8 c's packed per b128 write
  {
    int l = t & 63, g = t >> 6;
    const float* xn = x + ((size_t)n * CC) * LL + l0 + l;
#pragma unroll
    for (int i = 0; i < 8; i++) {
      int c8 = (i * 4 + g) * 8;
      union { short8 s; ushort u[8]; } p;
#pragma unroll
      for (int j = 0; j < 8; j++) p.u[j] = bf_rne(xn[(size_t)(c8 + j) * LL]);
      *(short8*)&xl[l * 264 + c8] = p.s;
    }
  }
  __syncthreads();

  f32x4 acc[2][2][4];
#pragma unroll
  for (int mt = 0; mt < 2; mt++)
#pragma unroll
    for (int ms = 0; ms < 2; ms++)
#pragma unroll
      for (int ls = 0; ls < 4; ls++) acc[mt][ms][ls] = (f32x4){0.f, 0.f, 0.f, 0.f};

#pragma unroll
  for (int kc = 0; kc < 8; kc++) {
    short8 a[2][2];
#pragma unroll
    for (int mt = 0; mt < 2; mt++)
#pragma unroll
      for (int ms = 0; ms < 2; ms++)
        a[mt][ms] = *(const short8*)(wqkbf +
            (((mt * 128 + wv * 32 + ms * 16 + m16) << 8) + kc * 32 + kg * 8));
#pragma unroll
    for (int ls = 0; ls < 4; ls++) {
      short8 b = *(const short8*)&xl[(ls * 16 + m16) * 264 + kc * 32 + kg * 8];
      acc[0][0][ls] =
          __builtin_amdgcn_mfma_f32_16x16x32_bf16(a[0][0], b, acc[0][0][ls], 0, 0, 0);
      acc[0][1][ls] =
          __builtin_amdgcn_mfma_f32_16x16x32_bf16(a[0][1], b, acc[0][1][ls], 0, 0, 0);
      acc[1][0][ls] =
          __builtin_amdgcn_mfma_f32_16x16x32_bf16(a[1][0], b, acc[1][0][ls], 0, 0, 0);
      acc[1][1][ls] =
          __builtin_amdgcn_mfma_f32_16x16x32_bf16(a[1][1], b, acc[1][1][ls], 0, 0, 0);
    }
  }

#pragma unroll
  for (int mt = 0; mt < 2; mt++) {
    float* outp = (mt ? k : q) + (size_t)n * IC * LL;
#pragma unroll
    for (int ms = 0; ms < 2; ms++)
#pragma unroll
      for (int ls = 0; ls < 4; ls++) {
        int col = l0 + ls * 16 + m16;
#pragma unroll
        for (int r = 0; r < 4; r++)
          outp[(size_t)(wv * 32 + ms * 16 + kg * 4 + r) * LL + col] =
              acc[mt][ms][ls][r];
      }
  }
}

// ---------------- K2: local 3x3 attention scores, f2 += 2*(q.k_patch) -------
__global__ __launch_bounds__(256) void k_attn(const float* __restrict__ q,
                                              const float* __restrict__ k,
                                              float* __restrict__ f2) {
  int n = blockIdx.x;
  int c0 = blockIdx.y * 32;
  int l = blockIdx.z * 256 + threadIdx.x;
  int h = l >> 5, w = l & 31;
  const float* qn = q + (size_t)n * IC * LL;
  const float* kn = k + (size_t)n * IC * LL;
  bool val[9];
  int off[9];
#pragma unroll
  for (int i = 0; i < 3; i++)
#pragma unroll
    for (int j = 0; j < 3; j++) {
      int r = i * 3 + j;
      int hh = h + i - 1, ww = w + j - 1;
      val[r] = (hh >= 0 && hh < 32 && ww >= 0 && ww < 32);
      off[r] = hh * 32 + ww;
    }
  float acc[9];
#pragma unroll
  for (int r = 0; r < 9; r++) acc[r] = 0.f;
#pragma unroll 4
  for (int cc = 0; cc < 32; cc++) {
    int c = c0 + cc;
    float qv = qn[c * LL + l];
    const float* kc = kn + c * LL;
#pragma unroll
    for (int r = 0; r < 9; r++) {
      float kv = val[r] ? kc[off[r]] : 0.f;
      acc[r] += qv * kv;
    }
  }
#pragma unroll
  for (int r = 0; r < 9; r++)
    atomicAdd(&f2[(size_t)n * DA + r * LL + l], 2.f * acc[r]);
}

// ---------------- K3: LayerNorm over 9216, in place -------------------------
__global__ __launch_bounds__(256) void k_ln1(float* __restrict__ f2,
                                             const float* __restrict__ g1,
                                             const float* __restrict__ b1) {
  int n = blockIdx.x, t = threadIdx.x;
  float* row = f2 + (size_t)n * DA;
  float4 v[9];
  float s = 0.f, ss = 0.f;
#pragma unroll
  for (int kk = 0; kk < 9; kk++) {
    v[kk] = ((const float4*)row)[t + kk * 256];
    s += v[kk].x + v[kk].y + v[kk].z + v[kk].w;
    ss += v[kk].x * v[kk].x + v[kk].y * v[kk].y + v[kk].z * v[kk].z +
          v[kk].w * v[kk].w;
  }
#pragma unroll
  for (int o = 32; o; o >>= 1) {
    s += __shfl_down(s, o);
    ss += __shfl_down(ss, o);
  }
  __shared__ float ps[4], pss[4], stats[2];
  int wid = t >> 6, lid = t & 63;
  if (lid == 0) { ps[wid] = s; pss[wid] = ss; }
  __syncthreads();
  if (t == 0) {
    float S = ps[0] + ps[1] + ps[2] + ps[3];
    float SS = pss[0] + pss[1] + pss[2] + pss[3];
    float mu = S / DA;
    float var = SS / DA - mu * mu;
    stats[0] = mu;
    stats[1] = rsqrtf(var + EPSF);
  }
  __syncthreads();
  float mu = stats[0], rs = stats[1];
#pragma unroll
  for (int kk = 0; kk < 9; kk++) {
    float4 g = ((const float4*)g1)[t + kk * 256];
    float4 b = ((const float4*)b1)[t + kk * 256];
    float4 o;
    o.x = (v[kk].x - mu) * rs * g.x + b.x;
    o.y = (v[kk].y - mu) * rs * g.y + b.y;
    o.z = (v[kk].z - mu) * rs * g.z + b.z;
    o.w = (v[kk].w - mu) * rs * g.w + b.w;
    ((float4*)row)[t + kk * 256] = o;
  }
}

// ---------------- K4: h1 = relu(fln @ w1^T + b1) -> bf16, n-split x4 --------
__global__ __launch_bounds__(256) void k_ffn1(const float* __restrict__ fln,
                                              const float* __restrict__ w1,
                                              const float* __restrict__ b1,
                                              ushort* __restrict__ h1bf) {
  int o = blockIdx.x, nsb = blockIdx.y * 8, t = threadIdx.x;
  float acc[8];
#pragma unroll
  for (int i = 0; i < 8; i++) acc[i] = 0.f;
  const float4* w1r = (const float4*)(w1 + (size_t)o * DA);
  for (int kk = 0; kk < 9; kk++) {
    float4 wv = w1r[t + kk * 256];
#pragma unroll
    for (int i = 0; i < 8; i++) {
      float4 fv = ((const float4*)(fln + (size_t)(nsb + i) * DA))[t + kk * 256];
      acc[i] += wv.x * fv.x + wv.y * fv.y + wv.z * fv.z + wv.w * fv.w;
    }
  }
#pragma unroll
  for (int i = 0; i < 8; i++)
#pragma unroll
    for (int s = 32; s; s >>= 1) acc[i] += __shfl_down(acc[i], s);
  __shared__ float part[4][8];
  int wid = t >> 6, lid = t & 63;
  if (lid == 0) {
#pragma unroll
    for (int i = 0; i < 8; i++) part[wid][i] = acc[i];
  }
  __syncthreads();
  if (t < 8) {
    float sum = part[0][t] + part[1][t] + part[2][t] + part[3][t] + b1[o];
    h1bf[(size_t)(nsb + t) * CC + o] = bf_rne(fmaxf(sum, 0.f));
  }
}

// ---------------- K5: h2 = h1 @ w2^T + b2 via bf16 MFMA ---------------------
// grid 512 (j-tiles of 256), 4 waves. Explicit 1-deep w2 prefetch; per-kc A
// loads (h1bf L1-hot, 16 KB). Stats: block LDS reduce + global atomicAdd into
// st (zeroed by the launch memset) -- k_stat dispatch eliminated.
__global__ __launch_bounds__(256, 3) void k_ffn2(
    const ushort* __restrict__ h1bf, const float* __restrict__ w2,
    const float* __restrict__ b2, float* __restrict__ h2,
    float* __restrict__ st) {
  __shared__ float bs[64];
  int t = threadIdx.x;
  int lane = t & 63, wv = t >> 6;
  int m16 = lane & 15, kg = lane >> 4;
  int j0 = blockIdx.x * 256 + wv * 64;
  if (t < 64) bs[t] = 0.f;

  int j[4];
#pragma unroll
  for (int nn = 0; nn < 4; nn++) j[nn] = j0 + nn * 16 + m16;

  f32x4 acc[2][4];
#pragma unroll
  for (int m = 0; m < 2; m++)
#pragma unroll
    for (int nn = 0; nn < 4; nn++) acc[m][nn] = (f32x4){0.f, 0.f, 0.f, 0.f};

  float4 lo[4], hi[4];
#pragma unroll
  for (int nn = 0; nn < 4; nn++) {
    const float* src = w2 + (size_t)j[nn] * CC + kg * 8;
    lo[nn] = *(const float4*)src;
    hi[nn] = *(const float4*)(src + 4);
  }

#pragma unroll
  for (int kc = 0; kc < 8; kc++) {
    short8 a0 = *(const short8*)(h1bf + m16 * CC + kc * 32 + kg * 8);
    short8 a1 = *(const short8*)(h1bf + (16 + m16) * CC + kc * 32 + kg * 8);
    short8 bf[4];
#pragma unroll
    for (int nn = 0; nn < 4; nn++) {
      union { short8 s; ushort u[8]; } cv;
      cv.u[0] = bf_rne(lo[nn].x); cv.u[1] = bf_rne(lo[nn].y);
      cv.u[2] = bf_rne(lo[nn].z); cv.u[3] = bf_rne(lo[nn].w);
      cv.u[4] = bf_rne(hi[nn].x); cv.u[5] = bf_rne(hi[nn].y);
      cv.u[6] = bf_rne(hi[nn].z); cv.u[7] = bf_rne(hi[nn].w);
      bf[nn] = cv.s;
    }
    if (kc < 7) {
#pragma unroll
      for (int nn = 0; nn < 4; nn++) {
        const float* src = w2 + (size_t)j[nn] * CC + (kc + 1) * 32 + kg * 8;
        lo[nn] = *(const float4*)src;
        hi[nn] = *(const float4*)(src + 4);
      }
    }
#pragma unroll
    for (int nn = 0; nn < 4; nn++) {
      acc[0][nn] =
          __builtin_amdgcn_mfma_f32_16x16x32_bf16(a0, bf[nn], acc[0][nn], 0, 0, 0);
      acc[1][nn] =
          __builtin_amdgcn_mfma_f32_16x16x32_bf16(a1, bf[nn], acc[1][nn], 0, 0, 0);
    }
  }
  __syncthreads();  // bs zero-init visible before LDS atomics

  float b2v[4];
#pragma unroll
  for (int nn = 0; nn < 4; nn++) b2v[nn] = b2[j[nn]];

  float s8[2][4], q8[2][4];
#pragma unroll
  for (int m = 0; m < 2; m++)
#pragma unroll
    for (int r = 0; r < 4; r++) { s8[m][r] = 0.f; q8[m][r] = 0.f; }
#pragma unroll
  for (int m = 0; m < 2; m++)
#pragma unroll
    for (int nn = 0; nn < 4; nn++) {
#pragma unroll
      for (int r = 0; r < 4; r++) {
        float v = acc[m][nn][r] + b2v[nn];
        int row = m * 16 + kg * 4 + r;
        h2[(size_t)row * DOUT + j[nn]] = v;
        s8[m][r] += v;
        q8[m][r] += v * v;
      }
    }
#pragma unroll
  for (int off = 8; off; off >>= 1)
#pragma unroll
    for (int m = 0; m < 2; m++)
#pragma unroll
      for (int r = 0; r < 4; r++) {
        s8[m][r] += __shfl_down(s8[m][r], off, 16);
        q8[m][r] += __shfl_down(q8[m][r], off, 16);
      }
  if (m16 == 0) {
#pragma unroll
    for (int m = 0; m < 2; m++)
#pragma unroll
      for (int r = 0; r < 4; r++) {
        int row = m * 16 + kg * 4 + r;
        atomicAdd(&bs[row], s8[m][r]);
        atomicAdd(&bs[32 + row], q8[m][r]);
      }
  }
  __syncthreads();
  if (t < 64) atomicAdd(&st[t], bs[t]);
}

// ---------------- K7: out = BN(LN2(h2)*g2+b2 @ w_out^T) + x via MFMA --------
// grid (16 l-tiles of 64, 32 n), 4 waves. h2 slice read ONCE (no Ob split),
// LN'd y staged bf16 in LDS [l][136] (minimal-conflict layout), 256x128x64
// MFMA tile per block. Wave = 64 output channels.
__global__ __launch_bounds__(256, 2) void k_out(
    const float* __restrict__ h2, const float* __restrict__ st,
    const float* __restrict__ g2, const float* __restrict__ b2,
    const ushort* __restrict__ wobf, const float* __restrict__ bn_g,
    const float* __restrict__ bn_b, const float* __restrict__ bn_m,
    const float* __restrict__ bn_v, const float* __restrict__ x,
    float* __restrict__ out) {
  __shared__ ushort yl[64 * 136];  // 17.4 KB
  int t = threadIdx.x;
  int n = blockIdx.y;
  int l0 = blockIdx.x * 64;
  float mu = st[n] * (1.f / DOUT);
  float rs = rsqrtf(st[32 + n] * (1.f / DOUT) - mu * mu + EPSF);

  {
    int l = t & 63, og = t >> 6;
    const float* h2n = h2 + (size_t)n * DOUT;
#pragma unroll
    for (int i = 0; i < 4; i++) {
      int o8 = (i * 4 + og) * 8;
      union { short8 s; ushort u[8]; } p;
#pragma unroll
      for (int jj = 0; jj < 8; jj++) {
        int d = (o8 + jj) * LL + l0 + l;
        float yv = (h2n[d] - mu) * rs * g2[d] + b2[d];
        p.u[jj] = bf_rne(yv);
      }
      *(short8*)&yl[l * 136 + o8] = p.s;
    }
  }
  __syncthreads();

  int lane = t & 63, wv = t >> 6;
  int m16 = lane & 15, kg = lane >> 4;
  f32x4 acc[4][4];
#pragma unroll
  for (int ms = 0; ms < 4; ms++)
#pragma unroll
    for (int ls = 0; ls < 4; ls++) acc[ms][ls] = (f32x4){0.f, 0.f, 0.f, 0.f};

#pragma unroll
  for (int kc = 0; kc < 4; kc++) {
    short8 a[4];
#pragma unroll
    for (int ms = 0; ms < 4; ms++)
      a[ms] = *(const short8*)(wobf +
          (((wv * 64 + ms * 16 + m16) << 7) + kc * 32 + kg * 8));
#pragma unroll
    for (int ls = 0; ls < 4; ls++) {
      short8 b = *(const short8*)&yl[(ls * 16 + m16) * 136 + kc * 32 + kg * 8];
#pragma unroll
      for (int ms = 0; ms < 4; ms++)
        acc[ms][ls] =
            __builtin_amdgcn_mfma_f32_16x16x32_bf16(a[ms], b, acc[ms][ls], 0, 0, 0);
    }
  }

#pragma unroll
  for (int ms = 0; ms < 4; ms++)
#pragma unroll
    for (int r = 0; r < 4; r++) {
      int O = wv * 64 + ms * 16 + kg * 4 + r;
      float sc = bn_g[O] * rsqrtf(bn_v[O] + EPSF);
      float sh = bn_b[O] - bn_m[O] * sc;
#pragma unroll
      for (int ls = 0; ls < 4; ls++) {
        int col = l0 + ls * 16 + m16;
        size_t base = ((size_t)(n * CC + O)) * LL + col;
        out[base] = acc[ms][ls][r] * sc + sh + x[base];
      }
    }
}

extern "C" void kernel_launch(void* const* d_in, const int* in_sizes, int n_in,
                              void* d_out, int out_size, void* d_ws,
                              size_t ws_size, hipStream_t stream) {
  const float* x = (const float*)d_in[0];
  const float* wq = (const float*)d_in[1];
  const float* wk = (const float*)d_in[2];
  const float* gamma1 = (const float*)d_in[3];
  const float* beta1 = (const float*)d_in[4];
  const float* w1 = (const float*)d_in[5];
  const float* b1 = (const float*)d_in[6];
  const float* w2 = (const float*)d_in[7];
  const float* b2 = (const float*)d_in[8];
  const float* gamma2 = (const float*)d_in[9];
  const float* beta2 = (const float*)d_in[10];
  const float* w_out = (const float*)d_in[11];
  const float* bn_g = (const float*)d_in[12];
  const float* bn_b = (const float*)d_in[13];
  const float* bn_m = (const float*)d_in[14];
  const float* bn_v = (const float*)d_in[15];
  float* outp = (float*)d_out;
  float* ws = (float*)d_ws;

  // ws layout (floats): q(4194304) | k(4194304) | f(294912) | st(64) |
  //   h1bf(4096) | wqkbf(32768) | wobf(16384). h2 aliases q.
  float* qb = ws;
  float* kb = ws + 4194304;
  float* fb = ws + 8388608;
  float* stb = ws + 8683520;
  ushort* h1bfb = (ushort*)(ws + 8683584);
  ushort* wqkbfb = (ushort*)(ws + 8687680);
  ushort* wobfb = (ushort*)(ws + 8720448);
  float* h2b = qb;

  if (ws_size < 8736832ull * sizeof(float)) return;  // fail visibly

  // zero f (attn atomics) AND st (ffn2 stat atomics) -- adjacent regions
  hipMemsetAsync(fb, 0, (294912 + 64) * sizeof(float), stream);
  k_wcvt<<<dim3(96), 256, 0, stream>>>(wq, wk, w_out, wqkbfb, wobfb);
  k_qkx<<<dim3(16, 32), 256, 0, stream>>>(x, wqkbfb, qb, kb);
  k_attn<<<dim3(32, 4, 4), 256, 0, stream>>>(qb, kb, fb);
  k_ln1<<<dim3(32), 256, 0, stream>>>(fb, gamma1, beta1);
  k_ffn1<<<dim3(256, 4), 256, 0, stream>>>(fb, w1, b1, h1bfb);
  k_ffn2<<<dim3(512), 256, 0, stream>>>(h1bfb, w2, b2, h2b, stb);
  k_out<<<dim3(16, 32), 256, 0, stream>>>(h2b, stb, gamma2, beta2, wobfb,
                                          bn_g, bn_b, bn_m, bn_v, x, outp);
}